// Round 1
// 554.994 us; speedup vs baseline: 1.1143x; 1.1143x over previous
//
#include <hip/hip_runtime.h>
#include <cstdint>
#include <cstddef>

typedef __bf16 bf16x8 __attribute__((ext_vector_type(8)));
typedef float f32x4 __attribute__((ext_vector_type(4)));
typedef unsigned short u16;
typedef u16 u16x4 __attribute__((ext_vector_type(4)));
typedef u16 u16x8 __attribute__((ext_vector_type(8)));

// fp32 -> bf16 round-to-nearest-even
__device__ __forceinline__ u16 f2bf(float f) {
  union { float f; unsigned u; } v; v.f = f;
  return (u16)((v.u + 0x7FFFu + ((v.u >> 16) & 1u)) >> 16);
}

// ---------------------------------------------------------------------------
// Pre-pass: gather (route) + fp32->bf16 + MFMA *fragment-major* layout.
// in:  [*, K, N] fp32 plane selected by route[z] (or z if route==null)
// out: frag-major bf16: out[(((a*NB + nb)*KT + kt)*64 + l)*8 + e]
//        = in[src][kt*32 + (l>>4)*8 + e][nb*16 + (l&15)]
// so a wave's B-fragment (nblk, kt) is 64 lanes x 16 B contiguous (1 KB).
// grid: (K/128, N/16, A); block 256 (4 fragments, kt = bx*4 + f)
// ---------------------------------------------------------------------------
__global__ void frag_cvt(const float* __restrict__ in, const int* __restrict__ route,
                         u16* __restrict__ out, int K, int N) {
  const int a = blockIdx.z;
  const int src = route ? route[a] : a;
  const int f = threadIdx.x >> 6, l = threadIdx.x & 63;
  const int r = l & 15, q = l >> 4;
  const int kt = blockIdx.x * 4 + f;
  const int nb = blockIdx.y;
  const int KT = K >> 5, NB = N >> 4;
  const float* ip = in + (size_t)src * K * N + (size_t)(kt * 32 + q * 8) * N + nb * 16 + r;
  u16x8 d;
#pragma unroll
  for (int e = 0; e < 8; ++e) d[e] = f2bf(ip[(size_t)e * N]);
  *(u16x8*)&out[((((size_t)a * NB + nb) * KT + kt) * 64 + l) * 8] = d;
}

// ---------------------------------------------------------------------------
// 64-row x 512-col x 512-k GEMM slice, per-wave n-slice of 64.
// A from LDS Xs (XOR-granule-swizzled, read-only, NO barriers),
// B frag-major from global (L2-resident), 1-deep register prefetch.
// ---------------------------------------------------------------------------
__device__ __forceinline__ void gemm64(const u16* __restrict__ Bw, const u16* __restrict__ Xs,
                                       int r, int q, f32x4 acc[4][4]) {
  bf16x8 bcur[4], bnxt[4];
#pragma unroll
  for (int nt = 0; nt < 4; ++nt) bcur[nt] = *(const bf16x8*)(Bw + nt * 8192);
#pragma unroll
  for (int kt = 0; kt < 16; ++kt) {
    if (kt < 15) {
#pragma unroll
      for (int nt = 0; nt < 4; ++nt)
        bnxt[nt] = *(const bf16x8*)(Bw + nt * 8192 + (kt + 1) * 512);
    }
#pragma unroll
    for (int mt = 0; mt < 4; ++mt) {
      const int m = mt * 16 + r;
      const bf16x8 af = *(const bf16x8*)&Xs[m * 512 + ((((kt << 2) + q) ^ (m & 7)) << 3)];
#pragma unroll
      for (int nt = 0; nt < 4; ++nt)   // swapped operands => lane holds m=r, n=q*4+reg
        acc[mt][nt] = __builtin_amdgcn_mfma_f32_16x16x32_bf16(bcur[nt], af, acc[mt][nt], 0, 0, 0);
    }
#pragma unroll
    for (int nt = 0; nt < 4; ++nt) bcur[nt] = bnxt[nt];
  }
}

// relu + bias epilogue, bf16 result into Xs (same XOR-granule swizzle)
__device__ __forceinline__ void epi_relu(u16* __restrict__ Xs, const float* __restrict__ bias,
                                         f32x4 acc[4][4], int w, int r, int q) {
#pragma unroll
  for (int mt = 0; mt < 4; ++mt) {
    const int m = mt * 16 + r;
#pragma unroll
    for (int nt = 0; nt < 4; ++nt) {
      const int col = w * 64 + nt * 16 + q * 4;
      const int gp = (col >> 3) ^ (m & 7);
      const float4 bb = *(const float4*)&bias[col];
      const f32x4 v = acc[mt][nt];
      const u16x4 d = { f2bf(fmaxf(v.x + bb.x, 0.f)), f2bf(fmaxf(v.y + bb.y, 0.f)),
                        f2bf(fmaxf(v.z + bb.z, 0.f)), f2bf(fmaxf(v.w + bb.w, 0.f)) };
      *(u16x4*)&Xs[m * 512 + gp * 8 + (q & 1) * 4] = d;
    }
  }
}

// ---------------------------------------------------------------------------
// Fused 3-layer MLP per (64-row batch tile, agent).
// Phase 0: x0 tile -> bf16 -> Xs (one barrier)
// Phase 1: X = relu(x0 @ Ws + bs)        A: Xs/LDS, B: global frag-major
// Phase 2: h = relu(X @ W1[a]^T + b1)    (h overwrites Xs)
// Phase 3: out = h @ W2[a]^T + b2        direct fp32 store
// 512 threads / 8 waves; NO k-loop barriers; 64 KB LDS -> 2 blocks/CU.
// ---------------------------------------------------------------------------
__global__ __launch_bounds__(512, 4)
void fused_mlp(const float* __restrict__ X0, const u16* __restrict__ Wsf,
               const float* __restrict__ bsh, const u16* __restrict__ W1f,
               const float* __restrict__ b1, const u16* __restrict__ W2f,
               const float* __restrict__ b2, const int* __restrict__ route,
               float* __restrict__ Out) {
  __shared__ u16 Xs[64 * 512];               // 64 KB

  const int tid = threadIdx.x;
  const int w = tid >> 6, l = tid & 63;
  const int r = l & 15, q = l >> 4;

  // XCD-pinned mapping: agent a lives on xcd = a>>2 (4 agents x 512 KB = 2 MB/L2)
  const int bid = blockIdx.x;
  const int xcd = bid & 7, idx = bid >> 3;   // nwg = 2048, 2048 % 8 == 0 (bijective)
  const int a = (xcd << 2) | (idx >> 6);
  const int b0 = (idx & 63) << 6;
  const int rt = route[a];

  // ======================= phase 0: x0 -> Xs (bf16, swizzled) ================
  {
    const float* gx = X0 + ((size_t)b0 * 32 + a) * 512;
#pragma unroll
    for (int i = 0; i < 8; ++i) {
      const int lin = i * 512 + tid;         // 0..4095
      const int m = lin >> 6, g = lin & 63;  // row, k-granule
      const float* p = gx + (size_t)m * (32 * 512) + g * 8;
      const float4 u = *(const float4*)p;
      const float4 v = *(const float4*)(p + 4);
      const u16x8 d = { f2bf(u.x), f2bf(u.y), f2bf(u.z), f2bf(u.w),
                        f2bf(v.x), f2bf(v.y), f2bf(v.z), f2bf(v.w) };
      *(u16x8*)&Xs[m * 512 + ((g ^ (m & 7)) << 3)] = d;
    }
  }
  __syncthreads();

  f32x4 acc[4][4];

  // ======================= phase 1 =======================
#pragma unroll
  for (int mt = 0; mt < 4; ++mt)
#pragma unroll
    for (int nt = 0; nt < 4; ++nt) acc[mt][nt] = (f32x4){0.f, 0.f, 0.f, 0.f};
  gemm64(Wsf + (w << 15) + l * 8, Xs, r, q, acc);
  __syncthreads();                           // all x0 reads done
  epi_relu(Xs, bsh, acc, w, r, q);
  __syncthreads();                           // X1 visible

  // ======================= phase 2 =======================
#pragma unroll
  for (int mt = 0; mt < 4; ++mt)
#pragma unroll
    for (int nt = 0; nt < 4; ++nt) acc[mt][nt] = (f32x4){0.f, 0.f, 0.f, 0.f};
  gemm64(W1f + (size_t)a * 262144 + (w << 15) + l * 8, Xs, r, q, acc);
  __syncthreads();                           // all X1 reads done
  epi_relu(Xs, b1 + (size_t)rt * 512, acc, w, r, q);
  __syncthreads();                           // h visible

  // ======================= phase 3 =======================
  {
    const int mt3 = w & 3, nt3 = w >> 2;     // out tile 64x32 = 8 frags, 1/wave
    const int m = mt3 * 16 + r;
    const u16* B2 = W2f + (size_t)a * 16384 + (nt3 << 13) + l * 8;
    f32x4 o = (f32x4){0.f, 0.f, 0.f, 0.f};
#pragma unroll
    for (int kt = 0; kt < 16; ++kt) {
      const bf16x8 af = *(const bf16x8*)&Xs[m * 512 + ((((kt << 2) + q) ^ (m & 7)) << 3)];
      const bf16x8 bf = *(const bf16x8*)(B2 + (kt << 9));
      o = __builtin_amdgcn_mfma_f32_16x16x32_bf16(bf, af, o, 0, 0, 0);
    }
    const int col = (nt3 << 4) + (q << 2);
    const float4 bb = *(const float4*)&b2[rt * 32 + col];
    const float4 res = { o.x + bb.x, o.y + bb.y, o.z + bb.z, o.w + bb.w };
    *(float4*)&Out[(size_t)(b0 + m) * 1024 + a * 32 + col] = res;
  }
}

// ---------------------------------------------------------------------------
extern "C" void kernel_launch(void* const* d_in, const int* in_sizes, int n_in,
                              void* d_out, int out_size, void* d_ws, size_t ws_size,
                              hipStream_t stream) {
  (void)in_sizes; (void)n_in; (void)out_size; (void)ws_size;
  const float* x0  = (const float*)d_in[0];
  const float* Wsh = (const float*)d_in[1];
  const float* bsh = (const float*)d_in[2];
  const float* W1  = (const float*)d_in[3];
  const float* b1  = (const float*)d_in[4];
  const float* W2  = (const float*)d_in[5];
  const float* b2  = (const float*)d_in[6];
  const int* route = (const int*)d_in[7];
  float* out = (float*)d_out;

  char* ws = (char*)d_ws;
  u16* Wsf = (u16*)(ws + 0);                      // 512*512*2    = 512 KB  frag-major
  u16* W1f = (u16*)(ws + 524288);                 // 32*512*512*2 = 16 MB   frag-major
  u16* W2f = (u16*)(ws + 524288 + 16777216);      // 32*32*512*2  = 1 MB    frag-major

  frag_cvt<<<dim3(4, 32, 1),  256, 0, stream>>>(Wsh, nullptr, Wsf, 512, 512);
  frag_cvt<<<dim3(4, 32, 32), 256, 0, stream>>>(W1, route, W1f, 512, 512);
  frag_cvt<<<dim3(4, 2, 32),  256, 0, stream>>>(W2, route, W2f, 512, 32);
  fused_mlp<<<dim3(2048), 512, 0, stream>>>(x0, Wsf, bsh, W1f, b1, W2f, b2, route, out);
}